// Round 7
// baseline (195.630 us; speedup 1.0000x reference)
//
#include <hip/hip_runtime.h>

// Actor MLP, B=262144 rows, fp32. 4 threads/row (quarters q, wave-uniform via
// readfirstlane -> all weight reads s_load/SGPR). R6 post-mortem: spill gone,
// but wall == scalar-VALU issue floor (~82us of v_fmac issue; fp32 peak needs
// VOP3P). Fix: v_pk_fma_f32 inline asm for phase2/3 (weight = SGPR pair
// source), z as 16 named f2v; single-pass phase3 (RPB=64, [4][64][31] fits);
// unroll 3 keeps 3 W3 s_load slices in flight.

typedef float f16v __attribute__((ext_vector_type(16)));
typedef float f4v  __attribute__((ext_vector_type(4)));
typedef float f2v  __attribute__((ext_vector_type(2)));

constexpr int NG = 14, GI = 9, FH = 128, AD = 15;
constexpr int RPB  = 64;    // rows per 256-thread block
constexpr int SSTR = 57;    // s region stride (odd -> conflict-free)
constexpr int PSTR = 31;    // partials stride (odd -> conflict-free)

// acc = w * v + acc   (w in SGPR pair, v/acc in VGPR pairs)
#define PKFMA(acc, wv, vv) \
    asm("v_pk_fma_f32 %0, %2, %1, %0" : "+v"(acc) : "v"(vv), "s"(wv))
// dst = w * v
#define PKMUL(dst, wv, vv) \
    asm("v_pk_mul_f32 %0, %2, %1" : "=v"(dst) : "v"(vv), "s"(wv))

__device__ __forceinline__ f4v load4u(const float* p) {
    f4v v; __builtin_memcpy(&v, p, 16); return v;   // 4B-aligned dwordx4
}

__global__ void w4t_kernel(const float* __restrict__ W4, float* __restrict__ W4T) {
    int t = blockIdx.x * 256 + threadIdx.x;
    if (t < FH * 2 * AD) {
        int j = t / (2 * AD), k = t % (2 * AD);   // W4[j][k]
        W4T[(size_t)k * FH + j] = W4[t];
    }
}

__global__ __launch_bounds__(256, 5) void actor_fused(
    const float* __restrict__ x,     // [B,126]
    const float* __restrict__ sale,  // [B,1]
    const float* __restrict__ W1,    // [9,16]
    const float* __restrict__ b1,    // [16]
    const float* __restrict__ W2,    // [16,4]
    const float* __restrict__ b2,    // [4]
    const float* __restrict__ W3,    // [57,128]
    const float* __restrict__ b3,    // [128]
    const float* __restrict__ W4T,   // [30,128] (transposed, in ws)
    const float* __restrict__ b4,    // [30]
    float* __restrict__ om, float* __restrict__ os, int B)
{
    // union: phase1/2 s values [64][57]=3648; phase3 partials [4][64][31]=7936
    __shared__ float smem[4 * RPB * PSTR];   // 31744 B

    const int tid = threadIdx.x;
    const int q   = __builtin_amdgcn_readfirstlane(tid >> 6);  // quarter 0..3
    const int r   = tid & (RPB - 1);
    const int row = blockIdx.x * RPB + r;

    // wave-uniform split: groups (4,4,3,3), z columns [32q, 32q+32)
    const int gbase = __builtin_amdgcn_readfirstlane(4 * q - (q == 3 ? 1 : 0));
    const int gcnt  = __builtin_amdgcn_readfirstlane(q >= 2 ? 3 : 4);
    const int zoff  = __builtin_amdgcn_readfirstlane(q * 32);

    const f16v* w1v = (const f16v*)W1;
    const f4v*  w2v = (const f4v*)W2;
    const f16v  b1v = *(const f16v*)b1;
    const f4v   b2v = *(const f4v*)b2;
    float* srow = smem + r * SSTR;

    // ---- phase 1: shared block for groups [gbase, gbase+gcnt) ----
    const float* xr = x + (size_t)row * (NG * GI);
    #pragma unroll 1
    for (int g = 0; g < gcnt; ++g) {
        const int gg = gbase + g;
        const float* xg = xr + gg * GI;
        f4v ca = load4u(xg), cb = load4u(xg + 4);
        float cs = xg[8];

        f16v h = b1v;
        h += ca[0] * w1v[0]; h += ca[1] * w1v[1]; h += ca[2] * w1v[2];
        h += ca[3] * w1v[3]; h += cb[0] * w1v[4]; h += cb[1] * w1v[5];
        h += cb[2] * w1v[6]; h += cb[3] * w1v[7]; h += cs    * w1v[8];
        h = __builtin_elementwise_max(h, (f16v)0.f);

        f4v s = b2v;
        s += h[0]  * w2v[0];  s += h[1]  * w2v[1];  s += h[2]  * w2v[2];  s += h[3]  * w2v[3];
        s += h[4]  * w2v[4];  s += h[5]  * w2v[5];  s += h[6]  * w2v[6];  s += h[7]  * w2v[7];
        s += h[8]  * w2v[8];  s += h[9]  * w2v[9];  s += h[10] * w2v[10]; s += h[11] * w2v[11];
        s += h[12] * w2v[12]; s += h[13] * w2v[13]; s += h[14] * w2v[14]; s += h[15] * w2v[15];
        s = __builtin_elementwise_max(s, (f4v)0.f);

        int c = gg * 4;
        srow[c + 0] = s[0]; srow[c + 1] = s[1];
        srow[c + 2] = s[2]; srow[c + 3] = s[3];
    }
    if (q == 3) srow[56] = sale[row];
    __syncthreads();

    // ---- phase 2: z-quarter[32] as 16 f2v; packed FMA, weights from SGPR ----
    const float* b3h = b3 + zoff;   // uniform -> s_load
    const float* w3q = W3 + zoff;   // uniform -> s_load
    f2v z0  = *(const f2v*)(b3h +  0), z1  = *(const f2v*)(b3h +  2);
    f2v z2  = *(const f2v*)(b3h +  4), z3  = *(const f2v*)(b3h +  6);
    f2v z4  = *(const f2v*)(b3h +  8), z5  = *(const f2v*)(b3h + 10);
    f2v z6  = *(const f2v*)(b3h + 12), z7  = *(const f2v*)(b3h + 14);
    f2v z8  = *(const f2v*)(b3h + 16), z9  = *(const f2v*)(b3h + 18);
    f2v z10 = *(const f2v*)(b3h + 20), z11 = *(const f2v*)(b3h + 22);
    f2v z12 = *(const f2v*)(b3h + 24), z13 = *(const f2v*)(b3h + 26);
    f2v z14 = *(const f2v*)(b3h + 28), z15 = *(const f2v*)(b3h + 30);

    #pragma unroll 3
    for (int c = 0; c < 57; ++c) {
        float sv = srow[c];
        f2v svp = {sv, sv};
        const f2v* wv = (const f2v*)(w3q + (size_t)c * FH);
        PKFMA(z0,  wv[0],  svp); PKFMA(z1,  wv[1],  svp);
        PKFMA(z2,  wv[2],  svp); PKFMA(z3,  wv[3],  svp);
        PKFMA(z4,  wv[4],  svp); PKFMA(z5,  wv[5],  svp);
        PKFMA(z6,  wv[6],  svp); PKFMA(z7,  wv[7],  svp);
        PKFMA(z8,  wv[8],  svp); PKFMA(z9,  wv[9],  svp);
        PKFMA(z10, wv[10], svp); PKFMA(z11, wv[11], svp);
        PKFMA(z12, wv[12], svp); PKFMA(z13, wv[13], svp);
        PKFMA(z14, wv[14], svp); PKFMA(z15, wv[15], svp);
    }
    z0  = __builtin_elementwise_max(z0,  (f2v)0.f);
    z1  = __builtin_elementwise_max(z1,  (f2v)0.f);
    z2  = __builtin_elementwise_max(z2,  (f2v)0.f);
    z3  = __builtin_elementwise_max(z3,  (f2v)0.f);
    z4  = __builtin_elementwise_max(z4,  (f2v)0.f);
    z5  = __builtin_elementwise_max(z5,  (f2v)0.f);
    z6  = __builtin_elementwise_max(z6,  (f2v)0.f);
    z7  = __builtin_elementwise_max(z7,  (f2v)0.f);
    z8  = __builtin_elementwise_max(z8,  (f2v)0.f);
    z9  = __builtin_elementwise_max(z9,  (f2v)0.f);
    z10 = __builtin_elementwise_max(z10, (f2v)0.f);
    z11 = __builtin_elementwise_max(z11, (f2v)0.f);
    z12 = __builtin_elementwise_max(z12, (f2v)0.f);
    z13 = __builtin_elementwise_max(z13, (f2v)0.f);
    z14 = __builtin_elementwise_max(z14, (f2v)0.f);
    z15 = __builtin_elementwise_max(z15, (f2v)0.f);
    __syncthreads();   // all s reads done; smem reused for partials

    // ---- phase 3: single pass, all quarters write their 30 partials ----
    float* prow = smem + ((size_t)q * RPB + r) * PSTR;
    #pragma unroll 1
    for (int k = 0; k < 2 * AD; ++k) {
        const f2v* wv = (const f2v*)(W4T + (size_t)k * FH + zoff);  // uniform
        f2v a;
        PKMUL(a, wv[0], z0);
        PKFMA(a, wv[1],  z1);  PKFMA(a, wv[2],  z2);  PKFMA(a, wv[3],  z3);
        PKFMA(a, wv[4],  z4);  PKFMA(a, wv[5],  z5);  PKFMA(a, wv[6],  z6);
        PKFMA(a, wv[7],  z7);  PKFMA(a, wv[8],  z8);  PKFMA(a, wv[9],  z9);
        PKFMA(a, wv[10], z10); PKFMA(a, wv[11], z11); PKFMA(a, wv[12], z12);
        PKFMA(a, wv[13], z13); PKFMA(a, wv[14], z14); PKFMA(a, wv[15], z15);
        prow[k] = a[0] + a[1];
    }
    __syncthreads();

    // ---- finalize: quarter q -> outputs [8q, 8q+8) (q3: 6) ----
    const int koff = q * 8;
    const int kcnt = (q == 3) ? 6 : 8;
    size_t ob = (size_t)row * AD;
    #pragma unroll 1
    for (int i = 0; i < kcnt; ++i) {
        int k = koff + i;
        float v = smem[(0 * RPB + r) * PSTR + k]
                + smem[(1 * RPB + r) * PSTR + k]
                + smem[(2 * RPB + r) * PSTR + k]
                + smem[(3 * RPB + r) * PSTR + k] + b4[k];
        if (k < AD) {
            float tc = fminf(fmaxf(v, -20.f), 20.f);
            float e = __expf(2.f * tc);
            om[ob + k] = (e - 1.f) / (e + 1.f);
        } else {
            os[ob + (k - AD)] = __expf(v);
        }
    }
}

extern "C" void kernel_launch(void* const* d_in, const int* in_sizes, int n_in,
                              void* d_out, int out_size, void* d_ws, size_t ws_size,
                              hipStream_t stream) {
    const float* x    = (const float*)d_in[0];
    const float* sale = (const float*)d_in[1];
    const float* W1   = (const float*)d_in[2];
    const float* b1   = (const float*)d_in[3];
    const float* W2   = (const float*)d_in[4];
    const float* b2   = (const float*)d_in[5];
    const float* W3   = (const float*)d_in[6];
    const float* b3   = (const float*)d_in[7];
    const float* W4   = (const float*)d_in[8];
    const float* b4   = (const float*)d_in[9];

    int B = in_sizes[1];                       // sale_predictions is [B,1]
    float* om = (float*)d_out;                 // action_mean flat [B*15]
    float* os = om + (size_t)B * AD;           // action_std  flat [B*15]
    float* W4T = (float*)d_ws;                 // [30,128]

    w4t_kernel<<<(FH * 2 * AD + 255) / 256, 256, 0, stream>>>(W4, W4T);
    int grid = B / RPB;                        // 4096 blocks
    actor_fused<<<grid, 256, 0, stream>>>(x, sale, W1, b1, W2, b2, W3, b3,
                                          W4T, b4, om, os, B);
}

// Round 8
// 171.207 us; speedup vs baseline: 1.1426x; 1.1426x over previous
//
#include <hip/hip_runtime.h>

// Actor MLP, B=262144 rows, fp32. 4 threads/row (quarters q=tid>>6, wave-
// uniform via readfirstlane -> all weight reads s_load). R7 post-mortem:
// inline-asm pk-FMA hurt scheduling; real lever is TLP (occupancy was LDS-
// capped at 5 blocks/CU). This round: plain C math (compiler schedules),
// LDS halved to 15.36 KB via two-half-pass phase 3 + transposed LDS layouts
// (s[c][row], p[q][k][row]: lane-consecutive -> conflict-free, imm-offset
// ds_read). __launch_bounds__(256,8) -> 8 blocks/CU, 32 waves/CU.

typedef float f16v __attribute__((ext_vector_type(16)));
typedef float f4v  __attribute__((ext_vector_type(4)));

constexpr int NG = 14, GI = 9, FH = 128, AD = 15;
constexpr int RPB = 64;     // rows per 256-thread block

__device__ __forceinline__ f4v load4u(const float* p) {
    f4v v; __builtin_memcpy(&v, p, 16); return v;   // 4B-aligned dwordx4
}

__global__ void w4t_kernel(const float* __restrict__ W4, float* __restrict__ W4T) {
    int t = blockIdx.x * 256 + threadIdx.x;
    if (t < FH * 2 * AD) {
        int j = t / (2 * AD), k = t % (2 * AD);   // W4[j][k]
        W4T[(size_t)k * FH + j] = W4[t];
    }
}

__global__ __launch_bounds__(256, 8) void actor_fused(
    const float* __restrict__ x,     // [B,126]
    const float* __restrict__ sale,  // [B,1]
    const float* __restrict__ W1,    // [9,16]
    const float* __restrict__ b1,    // [16]
    const float* __restrict__ W2,    // [16,4]
    const float* __restrict__ b2,    // [4]
    const float* __restrict__ W3,    // [57,128]
    const float* __restrict__ b3,    // [128]
    const float* __restrict__ W4T,   // [30,128] (transposed, in ws)
    const float* __restrict__ b4,    // [30]
    float* __restrict__ om, float* __restrict__ os, int B)
{
    // union in time:  s[c][row]  c<57            (3648 floats)
    //                 p[q][k][row] q<4,k<15      (3840 floats)
    __shared__ float smem[4 * AD * RPB];   // 15360 B

    const int tid = threadIdx.x;
    const int q   = __builtin_amdgcn_readfirstlane(tid >> 6);  // quarter 0..3
    const int r   = tid & (RPB - 1);
    const int row = blockIdx.x * RPB + r;

    // wave-uniform split: groups (4,4,3,3), z columns [32q, 32q+32)
    const int gbase = __builtin_amdgcn_readfirstlane(4 * q - (q == 3 ? 1 : 0));
    const int gcnt  = __builtin_amdgcn_readfirstlane(q >= 2 ? 3 : 4);
    const int zoff  = __builtin_amdgcn_readfirstlane(q * 32);

    const f16v* w1v = (const f16v*)W1;
    const f4v*  w2v = (const f4v*)W2;
    const f16v  b1v = *(const f16v*)b1;
    const f4v   b2v = *(const f4v*)b2;

    // ---- phase 1: shared block for groups [gbase, gbase+gcnt) ----
    const float* xr = x + (size_t)row * (NG * GI);
    #pragma unroll 1
    for (int g = 0; g < gcnt; ++g) {
        const int gg = gbase + g;
        const float* xg = xr + gg * GI;
        f4v ca = load4u(xg), cb = load4u(xg + 4);
        float cs = xg[8];

        f16v h = b1v;
        h += ca[0] * w1v[0]; h += ca[1] * w1v[1]; h += ca[2] * w1v[2];
        h += ca[3] * w1v[3]; h += cb[0] * w1v[4]; h += cb[1] * w1v[5];
        h += cb[2] * w1v[6]; h += cb[3] * w1v[7]; h += cs    * w1v[8];
        h = __builtin_elementwise_max(h, (f16v)0.f);

        f4v s = b2v;
        s += h[0]  * w2v[0];  s += h[1]  * w2v[1];  s += h[2]  * w2v[2];  s += h[3]  * w2v[3];
        s += h[4]  * w2v[4];  s += h[5]  * w2v[5];  s += h[6]  * w2v[6];  s += h[7]  * w2v[7];
        s += h[8]  * w2v[8];  s += h[9]  * w2v[9];  s += h[10] * w2v[10]; s += h[11] * w2v[11];
        s += h[12] * w2v[12]; s += h[13] * w2v[13]; s += h[14] * w2v[14]; s += h[15] * w2v[15];
        s = __builtin_elementwise_max(s, (f4v)0.f);

        int c0 = gg * 4;   // s[c][row] layout: word c*64 + r
        smem[(c0 + 0) * RPB + r] = s[0];
        smem[(c0 + 1) * RPB + r] = s[1];
        smem[(c0 + 2) * RPB + r] = s[2];
        smem[(c0 + 3) * RPB + r] = s[3];
    }
    if (q == 3) smem[56 * RPB + r] = sale[row];
    __syncthreads();

    // ---- phase 2: z-quarter[32] = relu(b3q + sum_c s[c]*W3[c][zoff..+32)) ----
    const float* b3h = b3 + zoff;   // uniform -> s_load
    const float* w3q = W3 + zoff;   // uniform -> s_load
    f4v z0 = load4u(b3h +  0), z1 = load4u(b3h +  4);
    f4v z2 = load4u(b3h +  8), z3 = load4u(b3h + 12);
    f4v z4 = load4u(b3h + 16), z5 = load4u(b3h + 20);
    f4v z6 = load4u(b3h + 24), z7 = load4u(b3h + 28);
    #pragma unroll 2
    for (int c = 0; c < 57; ++c) {
        float sv = smem[c * RPB + r];          // ds_read_b32, imm offset
        const f4v* wv = (const f4v*)(w3q + (size_t)c * FH);
        z0 += sv * wv[0]; z1 += sv * wv[1]; z2 += sv * wv[2]; z3 += sv * wv[3];
        z4 += sv * wv[4]; z5 += sv * wv[5]; z6 += sv * wv[6]; z7 += sv * wv[7];
    }
    z0 = __builtin_elementwise_max(z0, (f4v)0.f);
    z1 = __builtin_elementwise_max(z1, (f4v)0.f);
    z2 = __builtin_elementwise_max(z2, (f4v)0.f);
    z3 = __builtin_elementwise_max(z3, (f4v)0.f);
    z4 = __builtin_elementwise_max(z4, (f4v)0.f);
    z5 = __builtin_elementwise_max(z5, (f4v)0.f);
    z6 = __builtin_elementwise_max(z6, (f4v)0.f);
    z7 = __builtin_elementwise_max(z7, (f4v)0.f);
    __syncthreads();   // all s reads done; smem becomes partials region

    size_t ob = (size_t)row * AD;

    // ---- phase 3, half-pass over kbase in {0, 15} ----
    #pragma unroll 1
    for (int half = 0; half < 2; ++half) {
        const int kbase = half * AD;
        // partials: p[q][k][row] = word (q*15 + k)*64 + r
        #pragma unroll 1
        for (int k = 0; k < AD; ++k) {
            const f4v* wv = (const f4v*)(W4T + (size_t)(kbase + k) * FH + zoff);
            f4v a = z0 * wv[0];
            a += z1 * wv[1]; a += z2 * wv[2]; a += z3 * wv[3];
            a += z4 * wv[4]; a += z5 * wv[5]; a += z6 * wv[6]; a += z7 * wv[7];
            smem[(q * AD + k) * RPB + r] = (a[0] + a[1]) + (a[2] + a[3]);
        }
        __syncthreads();
        // finalize: quarter q handles k = 4q .. (q==3 ? 12+3 : 4q+4)
        const int kn = (q == 3) ? 3 : 4;
        #pragma unroll 1
        for (int i = 0; i < kn; ++i) {
            int k = 4 * q + i;
            float v = smem[(0 * AD + k) * RPB + r]
                    + smem[(1 * AD + k) * RPB + r]
                    + smem[(2 * AD + k) * RPB + r]
                    + smem[(3 * AD + k) * RPB + r] + b4[kbase + k];
            if (half == 0) {
                float tc = fminf(fmaxf(v, -20.f), 20.f);
                float e = __expf(2.f * tc);
                om[ob + k] = (e - 1.f) / (e + 1.f);
            } else {
                os[ob + k] = __expf(v);
            }
        }
        __syncthreads();
    }
}

extern "C" void kernel_launch(void* const* d_in, const int* in_sizes, int n_in,
                              void* d_out, int out_size, void* d_ws, size_t ws_size,
                              hipStream_t stream) {
    const float* x    = (const float*)d_in[0];
    const float* sale = (const float*)d_in[1];
    const float* W1   = (const float*)d_in[2];
    const float* b1   = (const float*)d_in[3];
    const float* W2   = (const float*)d_in[4];
    const float* b2   = (const float*)d_in[5];
    const float* W3   = (const float*)d_in[6];
    const float* b3   = (const float*)d_in[7];
    const float* W4   = (const float*)d_in[8];
    const float* b4   = (const float*)d_in[9];

    int B = in_sizes[1];                       // sale_predictions is [B,1]
    float* om = (float*)d_out;                 // action_mean flat [B*15]
    float* os = om + (size_t)B * AD;           // action_std  flat [B*15]
    float* W4T = (float*)d_ws;                 // [30,128]

    w4t_kernel<<<(FH * 2 * AD + 255) / 256, 256, 0, stream>>>(W4, W4T);
    int grid = B / RPB;                        // 4096 blocks
    actor_fused<<<grid, 256, 0, stream>>>(x, sale, W1, b1, W2, b2, W3, b3,
                                          W4T, b4, om, os, B);
}

// Round 9
// 127.347 us; speedup vs baseline: 1.5362x; 1.3444x over previous
//
#include <hip/hip_runtime.h>

// Actor MLP, B=262144 rows, fp32. 4 threads/row (quarters q=tid>>6, wave-
// uniform via readfirstlane -> all weight reads s_load). R8 post-mortem:
// (256,8) = 64-reg cap re-introduced scratch spill (WRITE 89MB, VGPR=32);
// occupancy 81% didn't pay because spill RMW + AGPR shuttling ate the gain.
// R9: identical structure, __launch_bounds__(256,6) -> 85-reg cap, no spill,
// 24 waves/CU. LDS stays 15.36 KB (transposed s[c][row] / p[q][k][row],
// conflict-free, imm-offset ds_read).

typedef float f16v __attribute__((ext_vector_type(16)));
typedef float f4v  __attribute__((ext_vector_type(4)));

constexpr int NG = 14, GI = 9, FH = 128, AD = 15;
constexpr int RPB = 64;     // rows per 256-thread block

__device__ __forceinline__ f4v load4u(const float* p) {
    f4v v; __builtin_memcpy(&v, p, 16); return v;   // 4B-aligned dwordx4
}

__global__ void w4t_kernel(const float* __restrict__ W4, float* __restrict__ W4T) {
    int t = blockIdx.x * 256 + threadIdx.x;
    if (t < FH * 2 * AD) {
        int j = t / (2 * AD), k = t % (2 * AD);   // W4[j][k]
        W4T[(size_t)k * FH + j] = W4[t];
    }
}

__global__ __launch_bounds__(256, 6) void actor_fused(
    const float* __restrict__ x,     // [B,126]
    const float* __restrict__ sale,  // [B,1]
    const float* __restrict__ W1,    // [9,16]
    const float* __restrict__ b1,    // [16]
    const float* __restrict__ W2,    // [16,4]
    const float* __restrict__ b2,    // [4]
    const float* __restrict__ W3,    // [57,128]
    const float* __restrict__ b3,    // [128]
    const float* __restrict__ W4T,   // [30,128] (transposed, in ws)
    const float* __restrict__ b4,    // [30]
    float* __restrict__ om, float* __restrict__ os, int B)
{
    // union in time:  s[c][row]  c<57            (3648 floats)
    //                 p[q][k][row] q<4,k<15      (3840 floats)
    __shared__ float smem[4 * AD * RPB];   // 15360 B

    const int tid = threadIdx.x;
    const int q   = __builtin_amdgcn_readfirstlane(tid >> 6);  // quarter 0..3
    const int r   = tid & (RPB - 1);
    const int row = blockIdx.x * RPB + r;

    // wave-uniform split: groups (4,4,3,3), z columns [32q, 32q+32)
    const int gbase = __builtin_amdgcn_readfirstlane(4 * q - (q == 3 ? 1 : 0));
    const int gcnt  = __builtin_amdgcn_readfirstlane(q >= 2 ? 3 : 4);
    const int zoff  = __builtin_amdgcn_readfirstlane(q * 32);

    const f16v* w1v = (const f16v*)W1;
    const f4v*  w2v = (const f4v*)W2;
    const f16v  b1v = *(const f16v*)b1;
    const f4v   b2v = *(const f4v*)b2;

    // ---- phase 1: shared block for groups [gbase, gbase+gcnt) ----
    const float* xr = x + (size_t)row * (NG * GI);
    #pragma unroll 1
    for (int g = 0; g < gcnt; ++g) {
        const int gg = gbase + g;
        const float* xg = xr + gg * GI;
        f4v ca = load4u(xg), cb = load4u(xg + 4);
        float cs = xg[8];

        f16v h = b1v;
        h += ca[0] * w1v[0]; h += ca[1] * w1v[1]; h += ca[2] * w1v[2];
        h += ca[3] * w1v[3]; h += cb[0] * w1v[4]; h += cb[1] * w1v[5];
        h += cb[2] * w1v[6]; h += cb[3] * w1v[7]; h += cs    * w1v[8];
        h = __builtin_elementwise_max(h, (f16v)0.f);

        f4v s = b2v;
        s += h[0]  * w2v[0];  s += h[1]  * w2v[1];  s += h[2]  * w2v[2];  s += h[3]  * w2v[3];
        s += h[4]  * w2v[4];  s += h[5]  * w2v[5];  s += h[6]  * w2v[6];  s += h[7]  * w2v[7];
        s += h[8]  * w2v[8];  s += h[9]  * w2v[9];  s += h[10] * w2v[10]; s += h[11] * w2v[11];
        s += h[12] * w2v[12]; s += h[13] * w2v[13]; s += h[14] * w2v[14]; s += h[15] * w2v[15];
        s = __builtin_elementwise_max(s, (f4v)0.f);

        int c0 = gg * 4;   // s[c][row] layout: word c*64 + r
        smem[(c0 + 0) * RPB + r] = s[0];
        smem[(c0 + 1) * RPB + r] = s[1];
        smem[(c0 + 2) * RPB + r] = s[2];
        smem[(c0 + 3) * RPB + r] = s[3];
    }
    if (q == 3) smem[56 * RPB + r] = sale[row];
    __syncthreads();

    // ---- phase 2: z-quarter[32] = relu(b3q + sum_c s[c]*W3[c][zoff..+32)) ----
    const float* b3h = b3 + zoff;   // uniform -> s_load
    const float* w3q = W3 + zoff;   // uniform -> s_load
    f4v z0 = load4u(b3h +  0), z1 = load4u(b3h +  4);
    f4v z2 = load4u(b3h +  8), z3 = load4u(b3h + 12);
    f4v z4 = load4u(b3h + 16), z5 = load4u(b3h + 20);
    f4v z6 = load4u(b3h + 24), z7 = load4u(b3h + 28);
    #pragma unroll 2
    for (int c = 0; c < 57; ++c) {
        float sv = smem[c * RPB + r];          // ds_read_b32, imm offset
        const f4v* wv = (const f4v*)(w3q + (size_t)c * FH);
        z0 += sv * wv[0]; z1 += sv * wv[1]; z2 += sv * wv[2]; z3 += sv * wv[3];
        z4 += sv * wv[4]; z5 += sv * wv[5]; z6 += sv * wv[6]; z7 += sv * wv[7];
    }
    z0 = __builtin_elementwise_max(z0, (f4v)0.f);
    z1 = __builtin_elementwise_max(z1, (f4v)0.f);
    z2 = __builtin_elementwise_max(z2, (f4v)0.f);
    z3 = __builtin_elementwise_max(z3, (f4v)0.f);
    z4 = __builtin_elementwise_max(z4, (f4v)0.f);
    z5 = __builtin_elementwise_max(z5, (f4v)0.f);
    z6 = __builtin_elementwise_max(z6, (f4v)0.f);
    z7 = __builtin_elementwise_max(z7, (f4v)0.f);
    __syncthreads();   // all s reads done; smem becomes partials region

    size_t ob = (size_t)row * AD;

    // ---- phase 3, half-pass over kbase in {0, 15} ----
    #pragma unroll 1
    for (int half = 0; half < 2; ++half) {
        const int kbase = half * AD;
        // partials: p[q][k][row] = word (q*15 + k)*64 + r
        #pragma unroll 1
        for (int k = 0; k < AD; ++k) {
            const f4v* wv = (const f4v*)(W4T + (size_t)(kbase + k) * FH + zoff);
            f4v a = z0 * wv[0];
            a += z1 * wv[1]; a += z2 * wv[2]; a += z3 * wv[3];
            a += z4 * wv[4]; a += z5 * wv[5]; a += z6 * wv[6]; a += z7 * wv[7];
            smem[(q * AD + k) * RPB + r] = (a[0] + a[1]) + (a[2] + a[3]);
        }
        __syncthreads();
        // finalize: quarter q handles k = 4q .. (q==3 ? 3 : 4 of them)
        const int kn = (q == 3) ? 3 : 4;
        #pragma unroll 1
        for (int i = 0; i < kn; ++i) {
            int k = 4 * q + i;
            float v = smem[(0 * AD + k) * RPB + r]
                    + smem[(1 * AD + k) * RPB + r]
                    + smem[(2 * AD + k) * RPB + r]
                    + smem[(3 * AD + k) * RPB + r] + b4[kbase + k];
            if (half == 0) {
                float tc = fminf(fmaxf(v, -20.f), 20.f);
                float e = __expf(2.f * tc);
                om[ob + k] = (e - 1.f) / (e + 1.f);
            } else {
                os[ob + k] = __expf(v);
            }
        }
        __syncthreads();
    }
}

extern "C" void kernel_launch(void* const* d_in, const int* in_sizes, int n_in,
                              void* d_out, int out_size, void* d_ws, size_t ws_size,
                              hipStream_t stream) {
    const float* x    = (const float*)d_in[0];
    const float* sale = (const float*)d_in[1];
    const float* W1   = (const float*)d_in[2];
    const float* b1   = (const float*)d_in[3];
    const float* W2   = (const float*)d_in[4];
    const float* b2   = (const float*)d_in[5];
    const float* W3   = (const float*)d_in[6];
    const float* b3   = (const float*)d_in[7];
    const float* W4   = (const float*)d_in[8];
    const float* b4   = (const float*)d_in[9];

    int B = in_sizes[1];                       // sale_predictions is [B,1]
    float* om = (float*)d_out;                 // action_mean flat [B*15]
    float* os = om + (size_t)B * AD;           // action_std  flat [B*15]
    float* W4T = (float*)d_ws;                 // [30,128]

    w4t_kernel<<<(FH * 2 * AD + 255) / 256, 256, 0, stream>>>(W4, W4T);
    int grid = B / RPB;                        // 4096 blocks
    actor_fused<<<grid, 256, 0, stream>>>(x, sale, W1, b1, W2, b2, W3, b3,
                                          W4T, b4, om, os, B);
}

// Round 10
// 66.888 us; speedup vs baseline: 2.9247x; 1.9039x over previous
//
#include <hip/hip_runtime.h>

// Actor MLP, B=262144 rows, fp32 in/out. R9 post-mortem: scalar fp32 VALU
// issue is pinned at ~80us across all structures -> only the matrix pipe
// breaks the floor. This round: phases 2+3 on MFMA (16x16x32 bf16) with
// split-bf16 (hi+lo) operands: A*B ~ hh + hl + lh, ~1e-4 rel err.
// Phase 1 (14x tiny 9->16->4 MLP) stays VALU. 64 rows/block, 4 waves.
// K-permutation of fragments cancels because A (LDS) and B (pre-packed in ws)
// use the same per-lane K-rule; only C/D layout (m89-verified) is load-bearing.

typedef float f4v  __attribute__((ext_vector_type(4)));
typedef float f16v __attribute__((ext_vector_type(16)));
typedef short s8v  __attribute__((ext_vector_type(8)));
typedef short s4v  __attribute__((ext_vector_type(4)));

constexpr int NG = 14, GI = 9, FH = 128, AD = 15;

__device__ __forceinline__ unsigned short f2bf(float f) {
    unsigned u = __builtin_bit_cast(unsigned, f);
    return (unsigned short)((u + 0x7fffu + ((u >> 16) & 1u)) >> 16);
}
__device__ __forceinline__ float bf2f(unsigned short h) {
    return __builtin_bit_cast(float, (unsigned)h << 16);
}
__device__ __forceinline__ f4v load4u(const float* p) {
    f4v v; __builtin_memcpy(&v, p, 16); return v;
}

// Pack W3 (57x128, K pad->64) and W4 (128x30, N pad->32) into per-lane
// B-fragment order: idx = ((kt*NT + nt)*64 + lane)*8 + j, element
// k = kt*32 + (lane>>4)*8 + j, n = nt*16 + (lane&15). hi/lo split-bf16.
__global__ void pack_kernel(const float* __restrict__ W3,
                            const float* __restrict__ W4,
                            unsigned short* __restrict__ pk) {
    unsigned short* W3h = pk;            // 8192 elems
    unsigned short* W3l = pk + 8192;     // 8192
    unsigned short* W4h = pk + 16384;    // 4096
    unsigned short* W4l = pk + 20480;    // 4096
    int t = blockIdx.x * 256 + threadIdx.x;
    if (t < 8192) {
        int j = t & 7, l = (t >> 3) & 63, nt = (t >> 9) & 7, kt = t >> 12;
        int k = kt * 32 + (l >> 4) * 8 + j, n = nt * 16 + (l & 15);
        float v = (k < 57) ? W3[k * FH + n] : 0.f;
        unsigned short h = f2bf(v);
        W3h[t] = h;
        W3l[t] = f2bf(v - bf2f(h));
    }
    if (t < 4096) {
        int j = t & 7, l = (t >> 3) & 63, nt = (t >> 9) & 1, kt = t >> 10;
        int k = kt * 32 + (l >> 4) * 8 + j, n = nt * 16 + (l & 15);
        float v = (n < 30) ? W4[k * 30 + n] : 0.f;
        unsigned short h = f2bf(v);
        W4h[t] = h;
        W4l[t] = f2bf(v - bf2f(h));
    }
}

__global__ __launch_bounds__(256, 4) void actor_fused(
    const float* __restrict__ x,     // [B,126]
    const float* __restrict__ sale,  // [B,1]
    const float* __restrict__ W1,    // [9,16]
    const float* __restrict__ b1,    // [16]
    const float* __restrict__ W2,    // [16,4]
    const float* __restrict__ b2,    // [4]
    const float* __restrict__ b3,    // [128]
    const float* __restrict__ b4,    // [30]
    const unsigned short* __restrict__ pk,
    float* __restrict__ om, float* __restrict__ os)
{
    // 16 KB total. Aliased in time:
    //   phase 1/2: s_hi/s_lo [64 rows][64 k] bf16 (XOR-swizzled rows)
    //   phase 3  : z_hi/z_lo [32 rows][128 k] bf16 (same 4096 elems each)
    __shared__ unsigned short sh[4096];
    __shared__ unsigned short sl[4096];

    const int tid  = threadIdx.x;
    const int wv   = __builtin_amdgcn_readfirstlane(tid >> 6);  // wave 0..3
    const int lane = tid & 63;
    const int r    = lane;                 // row within block (phase 1)
    const int row0 = blockIdx.x * 64;

    // ---------------- phase 1: VALU, groups split (4,4,3,3) ----------------
    const int gbase = __builtin_amdgcn_readfirstlane(4 * wv - (wv == 3 ? 1 : 0));
    const f16v* w1v = (const f16v*)W1;
    const f4v*  w2v = (const f4v*)W2;
    const f16v  b1v = *(const f16v*)b1;
    const f4v   b2v = *(const f4v*)b2;
    const float* xr = x + (size_t)(row0 + r) * (NG * GI);

    auto do_group = [&](int gg) {
        const float* xg = xr + gg * GI;
        f4v ca = load4u(xg), cb = load4u(xg + 4);
        float cs = xg[8];
        f16v h = b1v;
        h += ca[0]*w1v[0]; h += ca[1]*w1v[1]; h += ca[2]*w1v[2]; h += ca[3]*w1v[3];
        h += cb[0]*w1v[4]; h += cb[1]*w1v[5]; h += cb[2]*w1v[6]; h += cb[3]*w1v[7];
        h += cs*w1v[8];
        h = __builtin_elementwise_max(h, (f16v)0.f);
        f4v s = b2v;
        s += h[0]*w2v[0];  s += h[1]*w2v[1];  s += h[2]*w2v[2];  s += h[3]*w2v[3];
        s += h[4]*w2v[4];  s += h[5]*w2v[5];  s += h[6]*w2v[6];  s += h[7]*w2v[7];
        s += h[8]*w2v[8];  s += h[9]*w2v[9];  s += h[10]*w2v[10]; s += h[11]*w2v[11];
        s += h[12]*w2v[12]; s += h[13]*w2v[13]; s += h[14]*w2v[14]; s += h[15]*w2v[15];
        s = __builtin_elementwise_max(s, (f4v)0.f);
        unsigned short h0 = f2bf(s[0]), h1 = f2bf(s[1]),
                       h2 = f2bf(s[2]), h3 = f2bf(s[3]);
        s4v hi = (s4v){(short)h0, (short)h1, (short)h2, (short)h3};
        s4v lo = (s4v){(short)f2bf(s[0] - bf2f(h0)), (short)f2bf(s[1] - bf2f(h1)),
                       (short)f2bf(s[2] - bf2f(h2)), (short)f2bf(s[3] - bf2f(h3))};
        int byt = (r * 128 + gg * 8) ^ ((r & 7) << 4);   // k = gg*4 -> byte gg*8
        *(s4v*)((char*)sh + byt) = hi;
        *(s4v*)((char*)sl + byt) = lo;
    };
    if (wv < 2) { do_group(gbase+0); do_group(gbase+1); do_group(gbase+2); do_group(gbase+3); }
    else        { do_group(gbase+0); do_group(gbase+1); do_group(gbase+2); }
    if (wv == 3) {
        float sv = sale[row0 + r];
        unsigned short hb = f2bf(sv);
        int byt = (r * 128 + 112) ^ ((r & 7) << 4);      // k=56
        *(unsigned short*)((char*)sh + byt) = hb;
        *(unsigned short*)((char*)sl + byt) = f2bf(sv - bf2f(hb));
        #pragma unroll
        for (int kk = 57; kk < 64; ++kk) {               // zero K-pad
            int bb = (r * 128 + kk * 2) ^ ((r & 7) << 4);
            *(unsigned short*)((char*)sh + bb) = 0;
            *(unsigned short*)((char*)sl + bb) = 0;
        }
    }
    __syncthreads();

    // ---------------- phase 2: z[64,128] = s[64,64] @ W3  (MFMA) ----------
    const s8v* W3hv = (const s8v*)pk;
    const s8v* W3lv = (const s8v*)(pk + 8192);
    s8v bh[2][2], bl[2][2];
    #pragma unroll
    for (int kt = 0; kt < 2; ++kt)
        #pragma unroll
        for (int ntl = 0; ntl < 2; ++ntl) {
            int nt = 2 * wv + ntl;
            bh[kt][ntl] = W3hv[(kt * 8 + nt) * 64 + lane];
            bl[kt][ntl] = W3lv[(kt * 8 + nt) * 64 + lane];
        }
    f4v acc[4][2];
    #pragma unroll
    for (int ntl = 0; ntl < 2; ++ntl) {
        float bv = b3[32 * wv + ntl * 16 + (lane & 15)];
        #pragma unroll
        for (int mt = 0; mt < 4; ++mt) acc[mt][ntl] = (f4v){bv, bv, bv, bv};
    }
    #pragma unroll
    for (int kt = 0; kt < 2; ++kt) {
        s8v ah[4], al[4];
        #pragma unroll
        for (int mt = 0; mt < 4; ++mt) {
            int rr = mt * 16 + (lane & 15);
            int byt = (rr * 128 + kt * 64 + (lane >> 4) * 16) ^ ((rr & 7) << 4);
            ah[mt] = *(const s8v*)((char*)sh + byt);
            al[mt] = *(const s8v*)((char*)sl + byt);
        }
        #pragma unroll
        for (int mt = 0; mt < 4; ++mt)
            #pragma unroll
            for (int ntl = 0; ntl < 2; ++ntl) {
                acc[mt][ntl] = __builtin_amdgcn_mfma_f32_16x16x32_bf16(ah[mt], bh[kt][ntl], acc[mt][ntl], 0, 0, 0);
                acc[mt][ntl] = __builtin_amdgcn_mfma_f32_16x16x32_bf16(ah[mt], bl[kt][ntl], acc[mt][ntl], 0, 0, 0);
                acc[mt][ntl] = __builtin_amdgcn_mfma_f32_16x16x32_bf16(al[mt], bh[kt][ntl], acc[mt][ntl], 0, 0, 0);
            }
    }

    // ------- phase 3: out[64,30] = relu(z)[64,128] @ W4, in two row-halves --
    const s8v* W4hv = (const s8v*)(pk + 16384);
    const s8v* W4lv = (const s8v*)(pk + 20480);
    const int mtt  = __builtin_amdgcn_readfirstlane(wv >> 1);
    const int ntt  = __builtin_amdgcn_readfirstlane(wv & 1);
    const int ocol = ntt * 16 + (lane & 15);
    const float b4i = (ocol < 30) ? b4[ocol] : 0.f;

    #pragma unroll
    for (int half = 0; half < 2; ++half) {
        __syncthreads();   // h0: all phase-2 s-reads done; h1: h0 z-reads done
        // stage relu(z) rows [32*half, 32*half+32) as bf16 hi/lo
        #pragma unroll
        for (int mtl = 0; mtl < 2; ++mtl) {
            const int mt = 2 * half + mtl;
            #pragma unroll
            for (int ntl = 0; ntl < 2; ++ntl) {
                const int col = 32 * wv + ntl * 16 + (lane & 15);
                #pragma unroll
                for (int i = 0; i < 4; ++i) {
                    int rowl = mtl * 16 + (lane >> 4) * 4 + i;   // m89 C/D map
                    float v = fmaxf(acc[mt][ntl][i], 0.f);
                    unsigned short hb = f2bf(v);
                    int byt = (rowl * 256 + col * 2) ^ ((rowl & 7) << 4);
                    *(unsigned short*)((char*)sh + byt) = hb;
                    *(unsigned short*)((char*)sl + byt) = f2bf(v - bf2f(hb));
                }
            }
        }
        __syncthreads();
        f4v oa = (f4v){b4i, b4i, b4i, b4i};
        #pragma unroll
        for (int kt = 0; kt < 4; ++kt) {
            int rr = mtt * 16 + (lane & 15);
            int byt = (rr * 256 + kt * 64 + (lane >> 4) * 16) ^ ((rr & 7) << 4);
            s8v zh = *(const s8v*)((char*)sh + byt);
            s8v zl = *(const s8v*)((char*)sl + byt);
            s8v wh = W4hv[(kt * 2 + ntt) * 64 + lane];
            s8v wl = W4lv[(kt * 2 + ntt) * 64 + lane];
            oa = __builtin_amdgcn_mfma_f32_16x16x32_bf16(zh, wh, oa, 0, 0, 0);
            oa = __builtin_amdgcn_mfma_f32_16x16x32_bf16(zh, wl, oa, 0, 0, 0);
            oa = __builtin_amdgcn_mfma_f32_16x16x32_bf16(zl, wh, oa, 0, 0, 0);
        }
        #pragma unroll
        for (int i = 0; i < 4; ++i) {
            int grow = row0 + half * 32 + mtt * 16 + (lane >> 4) * 4 + i;
            float v = oa[i];
            if (ocol < AD) {
                float tc = fminf(fmaxf(v, -20.f), 20.f);
                float e = __expf(2.f * tc);
                om[(size_t)grow * AD + ocol] = (e - 1.f) / (e + 1.f);
            } else if (ocol < 2 * AD) {
                os[(size_t)grow * AD + (ocol - AD)] = __expf(v);
            }
        }
    }
}

extern "C" void kernel_launch(void* const* d_in, const int* in_sizes, int n_in,
                              void* d_out, int out_size, void* d_ws, size_t ws_size,
                              hipStream_t stream) {
    const float* x    = (const float*)d_in[0];
    const float* sale = (const float*)d_in[1];
    const float* W1   = (const float*)d_in[2];
    const float* b1   = (const float*)d_in[3];
    const float* W2   = (const float*)d_in[4];
    const float* b2   = (const float*)d_in[5];
    const float* W3   = (const float*)d_in[6];
    const float* b3   = (const float*)d_in[7];
    const float* W4   = (const float*)d_in[8];
    const float* b4   = (const float*)d_in[9];

    int B = in_sizes[1];                       // sale_predictions is [B,1]
    float* om = (float*)d_out;                 // action_mean flat [B*15]
    float* os = om + (size_t)B * AD;           // action_std  flat [B*15]
    unsigned short* pk = (unsigned short*)d_ws;  // 24576 bf16 = 48 KB

    pack_kernel<<<32, 256, 0, stream>>>(W3, W4, pk);
    actor_fused<<<B / 64, 256, 0, stream>>>(x, sale, W1, b1, W2, b2,
                                            b3, b4, pk, om, os);
}